// Round 9
// baseline (234.761 us; speedup 1.0000x reference)
//
#include <hip/hip_runtime.h>

#define N_NODES 50000
#define N_EDGES 640000
#define IN_CH 128
#define OUT_CH 128
#define HID 256
#define M_PAD 50048                    // 782 * 64
#define CAP 64                         // per-node edge capacity (Poisson(12.8): P(>=64)~1e-27)

typedef unsigned int uint;
typedef unsigned short ushort;

// ---------- bf16 helpers (RNE) ----------
__device__ __forceinline__ ushort f2b(float f) {
    uint u = __float_as_uint(f);
    u += 0x7FFFu + ((u >> 16) & 1u);
    return (ushort)(u >> 16);
}
__device__ __forceinline__ float b2f_lo(uint u) { return __uint_as_float(u << 16); }
__device__ __forceinline__ float b2f_hi(uint u) { return __uint_as_float(u & 0xFFFF0000u); }
__device__ __forceinline__ uint packb(float lo, float hi) {
    return (uint)f2b(lo) | ((uint)f2b(hi) << 16);
}

// ---------- async global->LDS 16B ----------
__device__ __forceinline__ void gload_lds16(const ushort* g, ushort* l) {
    __builtin_amdgcn_global_load_lds(
        (const __attribute__((address_space(1))) void*)g,
        (__attribute__((address_space(3))) void*)l, 16, 0, 0);
}

// ================= prep: direct CSR bucketing + all casts, one dispatch =======
// blocks 0..624: edges, 4/thread via int4 (p = atomicAdd(cnt[dst]); col[dst*64+p]=src)
// blocks 625..4261: x cast -> xcat right half; weights -> fragment-major bf16
__global__ __launch_bounds__(256) void prep(
    const int* __restrict__ src, const int* __restrict__ dst,
    const float* __restrict__ x, const float* __restrict__ w1l,
    const float* __restrict__ w1r, const float* __restrict__ w2l,
    const float* __restrict__ w2r, int* __restrict__ cnt,
    ushort* __restrict__ col, ushort* __restrict__ xcat,
    ushort* __restrict__ w1f, ushort* __restrict__ w2f) {
    int b = blockIdx.x;
    if (b < 625) {
        int base = (b * 256 + threadIdx.x) * 4;   // 4 edges/thread, 640000 total
        int4 d4 = *(const int4*)(dst + base);
        int4 s4 = *(const int4*)(src + base);
        int p0 = atomicAdd(&cnt[d4.x], 1);
        int p1 = atomicAdd(&cnt[d4.y], 1);
        int p2 = atomicAdd(&cnt[d4.z], 1);
        int p3 = atomicAdd(&cnt[d4.w], 1);
        if (p0 < CAP) col[d4.x * CAP + p0] = (ushort)s4.x;
        if (p1 < CAP) col[d4.y * CAP + p1] = (ushort)s4.y;
        if (p2 < CAP) col[d4.z * CAP + p2] = (ushort)s4.z;
        if (p3 < CAP) col[d4.w * CAP + p3] = (ushort)s4.w;
    } else {
        int id = (b - 625) * 256 + threadIdx.x;  // 0 .. 931071
        if (id < 800000) {                  // x: 8 floats/thread
            long long base = (long long)id * 8;
            float4 a = *(const float4*)(x + base);
            float4 c = *(const float4*)(x + base + 4);
            uint4 o;
            o.x = packb(a.x, a.y);
            o.y = packb(a.z, a.w);
            o.z = packb(c.x, c.y);
            o.w = packb(c.z, c.w);
            int row = id >> 4;
            int cc = id & 15;
            ((uint4*)xcat)[(size_t)row * 32 + 16 + cc] = o;
        } else if (id < 865536) {
            int i = id - 800000;
            int n0 = i >> 12, kk = (i >> 9) & 7, lane = (i >> 3) & 63, j = i & 7;
            int n = n0 * 16 + (lane & 15);
            int k = kk * 32 + (lane >> 4) * 8 + j;
            float v = (k < 128) ? w1l[k * 256 + n] : w1r[(k - 128) * 256 + n];
            w1f[i] = f2b(v);
        } else {
            int i = id - 865536;
            int n0 = i >> 12, kk = (i >> 9) & 7, lane = (i >> 3) & 63, j = i & 7;
            int n = n0 * 16 + (lane & 15);
            int k = kk * 32 + (lane >> 4) * 8 + j;
            float v = (n < 128) ? w2l[k * 128 + n] : w2r[k * 128 + (n - 128)];
            w2f[i] = f2b(v);
        }
    }
}

// ====== layer-1 gather mean -> LEFT half of xcat; 16 thr/node, 8x unroll ======
__global__ __launch_bounds__(256) void aggregate_mean1(
    const int* __restrict__ cnt, const ushort* __restrict__ col,
    ushort* __restrict__ xcat) {
    int t = blockIdx.x * 256 + threadIdx.x;
    int node = t >> 4;
    int q = t & 15;
    if (node >= N_NODES) return;
    int degf = cnt[node];
    int deg = min(degf, CAP);
    const ushort* cb = col + node * CAP;
    float acc[8] = {0.f, 0.f, 0.f, 0.f, 0.f, 0.f, 0.f, 0.f};
    const uint4* f4 = (const uint4*)xcat;
    int j = 0;
    for (; j + 8 <= deg; j += 8) {
        uint4 c4 = *(const uint4*)(cb + j);   // 8 ushort ids
        int s0 = c4.x & 0xFFFF, s1 = c4.x >> 16;
        int s2 = c4.y & 0xFFFF, s3 = c4.y >> 16;
        int s4 = c4.z & 0xFFFF, s5 = c4.z >> 16;
        int s6 = c4.w & 0xFFFF, s7 = c4.w >> 16;
        uint4 v0 = f4[(size_t)s0 * 32 + 16 + q];
        uint4 v1 = f4[(size_t)s1 * 32 + 16 + q];
        uint4 v2 = f4[(size_t)s2 * 32 + 16 + q];
        uint4 v3 = f4[(size_t)s3 * 32 + 16 + q];
        uint4 v4 = f4[(size_t)s4 * 32 + 16 + q];
        uint4 v5 = f4[(size_t)s5 * 32 + 16 + q];
        uint4 v6 = f4[(size_t)s6 * 32 + 16 + q];
        uint4 v7 = f4[(size_t)s7 * 32 + 16 + q];
        acc[0] += b2f_lo(v0.x) + b2f_lo(v1.x) + b2f_lo(v2.x) + b2f_lo(v3.x)
                + b2f_lo(v4.x) + b2f_lo(v5.x) + b2f_lo(v6.x) + b2f_lo(v7.x);
        acc[1] += b2f_hi(v0.x) + b2f_hi(v1.x) + b2f_hi(v2.x) + b2f_hi(v3.x)
                + b2f_hi(v4.x) + b2f_hi(v5.x) + b2f_hi(v6.x) + b2f_hi(v7.x);
        acc[2] += b2f_lo(v0.y) + b2f_lo(v1.y) + b2f_lo(v2.y) + b2f_lo(v3.y)
                + b2f_lo(v4.y) + b2f_lo(v5.y) + b2f_lo(v6.y) + b2f_lo(v7.y);
        acc[3] += b2f_hi(v0.y) + b2f_hi(v1.y) + b2f_hi(v2.y) + b2f_hi(v3.y)
                + b2f_hi(v4.y) + b2f_hi(v5.y) + b2f_hi(v6.y) + b2f_hi(v7.y);
        acc[4] += b2f_lo(v0.z) + b2f_lo(v1.z) + b2f_lo(v2.z) + b2f_lo(v3.z)
                + b2f_lo(v4.z) + b2f_lo(v5.z) + b2f_lo(v6.z) + b2f_lo(v7.z);
        acc[5] += b2f_hi(v0.z) + b2f_hi(v1.z) + b2f_hi(v2.z) + b2f_hi(v3.z)
                + b2f_hi(v4.z) + b2f_hi(v5.z) + b2f_hi(v6.z) + b2f_hi(v7.z);
        acc[6] += b2f_lo(v0.w) + b2f_lo(v1.w) + b2f_lo(v2.w) + b2f_lo(v3.w)
                + b2f_lo(v4.w) + b2f_lo(v5.w) + b2f_lo(v6.w) + b2f_lo(v7.w);
        acc[7] += b2f_hi(v0.w) + b2f_hi(v1.w) + b2f_hi(v2.w) + b2f_hi(v3.w)
                + b2f_hi(v4.w) + b2f_hi(v5.w) + b2f_hi(v6.w) + b2f_hi(v7.w);
    }
    for (; j < deg; ++j) {
        uint4 v = f4[(size_t)cb[j] * 32 + 16 + q];
        acc[0] += b2f_lo(v.x); acc[1] += b2f_hi(v.x);
        acc[2] += b2f_lo(v.y); acc[3] += b2f_hi(v.y);
        acc[4] += b2f_lo(v.z); acc[5] += b2f_hi(v.z);
        acc[6] += b2f_lo(v.w); acc[7] += b2f_hi(v.w);
    }
    float inv = 1.0f / fmaxf((float)degf, 1.0f);
    uint4 o;
    o.x = packb(acc[0] * inv, acc[1] * inv);
    o.y = packb(acc[2] * inv, acc[3] * inv);
    o.z = packb(acc[4] * inv, acc[5] * inv);
    o.w = packb(acc[6] * inv, acc[7] * inv);
    ((uint4*)xcat)[(size_t)node * 32 + q] = o;
}

// ========== layer-2 combine: out = mean_gather(hw_l) + hw_r + bias ==========
__global__ __launch_bounds__(256) void combine2(
    const ushort* __restrict__ hw, const int* __restrict__ cnt,
    const ushort* __restrict__ col, const float* __restrict__ bias,
    float* __restrict__ out) {
    int t = blockIdx.x * 256 + threadIdx.x;
    int node = t >> 4;
    int q = t & 15;
    if (node >= N_NODES) return;
    int degf = cnt[node];
    int deg = min(degf, CAP);
    const ushort* cb = col + node * CAP;
    float acc[8] = {0.f, 0.f, 0.f, 0.f, 0.f, 0.f, 0.f, 0.f};
    const uint4* f4 = (const uint4*)hw;
    int j = 0;
    for (; j + 8 <= deg; j += 8) {
        uint4 c4 = *(const uint4*)(cb + j);
        int s0 = c4.x & 0xFFFF, s1 = c4.x >> 16;
        int s2 = c4.y & 0xFFFF, s3 = c4.y >> 16;
        int s4 = c4.z & 0xFFFF, s5 = c4.z >> 16;
        int s6 = c4.w & 0xFFFF, s7 = c4.w >> 16;
        uint4 v0 = f4[(size_t)s0 * 32 + q];
        uint4 v1 = f4[(size_t)s1 * 32 + q];
        uint4 v2 = f4[(size_t)s2 * 32 + q];
        uint4 v3 = f4[(size_t)s3 * 32 + q];
        uint4 v4 = f4[(size_t)s4 * 32 + q];
        uint4 v5 = f4[(size_t)s5 * 32 + q];
        uint4 v6 = f4[(size_t)s6 * 32 + q];
        uint4 v7 = f4[(size_t)s7 * 32 + q];
        acc[0] += b2f_lo(v0.x) + b2f_lo(v1.x) + b2f_lo(v2.x) + b2f_lo(v3.x)
                + b2f_lo(v4.x) + b2f_lo(v5.x) + b2f_lo(v6.x) + b2f_lo(v7.x);
        acc[1] += b2f_hi(v0.x) + b2f_hi(v1.x) + b2f_hi(v2.x) + b2f_hi(v3.x)
                + b2f_hi(v4.x) + b2f_hi(v5.x) + b2f_hi(v6.x) + b2f_hi(v7.x);
        acc[2] += b2f_lo(v0.y) + b2f_lo(v1.y) + b2f_lo(v2.y) + b2f_lo(v3.y)
                + b2f_lo(v4.y) + b2f_lo(v5.y) + b2f_lo(v6.y) + b2f_lo(v7.y);
        acc[3] += b2f_hi(v0.y) + b2f_hi(v1.y) + b2f_hi(v2.y) + b2f_hi(v3.y)
                + b2f_hi(v4.y) + b2f_hi(v5.y) + b2f_hi(v6.y) + b2f_hi(v7.y);
        acc[4] += b2f_lo(v0.z) + b2f_lo(v1.z) + b2f_lo(v2.z) + b2f_lo(v3.z)
                + b2f_lo(v4.z) + b2f_lo(v5.z) + b2f_lo(v6.z) + b2f_lo(v7.z);
        acc[5] += b2f_hi(v0.z) + b2f_hi(v1.z) + b2f_hi(v2.z) + b2f_hi(v3.z)
                + b2f_hi(v4.z) + b2f_hi(v5.z) + b2f_hi(v6.z) + b2f_hi(v7.z);
        acc[6] += b2f_lo(v0.w) + b2f_lo(v1.w) + b2f_lo(v2.w) + b2f_lo(v3.w)
                + b2f_lo(v4.w) + b2f_lo(v5.w) + b2f_lo(v6.w) + b2f_lo(v7.w);
        acc[7] += b2f_hi(v0.w) + b2f_hi(v1.w) + b2f_hi(v2.w) + b2f_hi(v3.w)
                + b2f_hi(v4.w) + b2f_hi(v5.w) + b2f_hi(v6.w) + b2f_hi(v7.w);
    }
    for (; j < deg; ++j) {
        uint4 v = f4[(size_t)cb[j] * 32 + q];
        acc[0] += b2f_lo(v.x); acc[1] += b2f_hi(v.x);
        acc[2] += b2f_lo(v.y); acc[3] += b2f_hi(v.y);
        acc[4] += b2f_lo(v.z); acc[5] += b2f_hi(v.z);
        acc[6] += b2f_lo(v.w); acc[7] += b2f_hi(v.w);
    }
    float inv = 1.0f / fmaxf((float)degf, 1.0f);
    uint4 r = f4[(size_t)node * 32 + 16 + q];
    float4 b0 = *(const float4*)(bias + q * 8);
    float4 b1 = *(const float4*)(bias + q * 8 + 4);
    float4 o0, o1;
    o0.x = acc[0] * inv + b2f_lo(r.x) + b0.x;
    o0.y = acc[1] * inv + b2f_hi(r.x) + b0.y;
    o0.z = acc[2] * inv + b2f_lo(r.y) + b0.z;
    o0.w = acc[3] * inv + b2f_hi(r.y) + b0.w;
    o1.x = acc[4] * inv + b2f_lo(r.z) + b1.x;
    o1.y = acc[5] * inv + b2f_hi(r.z) + b1.y;
    o1.z = acc[6] * inv + b2f_lo(r.w) + b1.z;
    o1.w = acc[7] * inv + b2f_hi(r.w) + b1.w;
    *(float4*)(out + (size_t)node * 128 + q * 8) = o0;
    *(float4*)(out + (size_t)node * 128 + q * 8 + 4) = o1;
}

// ================= fused double GEMM, 64-row tile, depth-2 B pipeline ========
using bf16x8 = __attribute__((ext_vector_type(8))) short;
using f32x4  = __attribute__((ext_vector_type(4))) float;

__global__ __launch_bounds__(256) void fused_gemm(
    const ushort* __restrict__ A, const ushort* __restrict__ w1f,
    const ushort* __restrict__ w2f, const float* __restrict__ b1,
    ushort* __restrict__ hw) {
    __shared__ alignas(16) ushort tile[64 * 256];  // 32 KB

    const int tid = threadIdx.x;
    const int lane = tid & 63;
    const int wave = tid >> 6;
    const int quad = lane >> 4;
    const int l16 = lane & 15;
    const int bm = blockIdx.x * 64;

    // ---- stage A tile (64 rows x 256 k): 8 issues, src-chunk XOR swizzle ----
#pragma unroll
    for (int r = 0; r < 8; ++r) {
        int row = r * 8 + (tid >> 5);
        int c = tid & 31;
        int src = (c & 24) | ((c & 7) ^ (row & 7));
        gload_lds16(A + (size_t)(bm + row) * 256 + src * 8, &tile[row * 256 + c * 8]);
    }

    f32x4 acc[4][4];
#pragma unroll
    for (int rt = 0; rt < 4; ++rt)
#pragma unroll
        for (int ct = 0; ct < 4; ++ct) acc[rt][ct] = (f32x4){0.f, 0.f, 0.f, 0.f};

    const size_t bstep = 64 * 8;  // one kk step
    const ushort* w1b = w1f + (((size_t)(wave * 4) * 8) * 64 + lane) * 8;
    const ushort* w2b = w2f + (((size_t)(wave * 4) * 8) * 64 + lane) * 8;

    // depth-2 B pipeline: bp[kk&1] holds step kk's frags
    bf16x8 bp[2][4];
#pragma unroll
    for (int ct = 0; ct < 4; ++ct) {
        bp[0][ct] = *(const bf16x8*)(w1b + ((size_t)ct * 8 + 0) * bstep);
        bp[1][ct] = *(const bf16x8*)(w1b + ((size_t)ct * 8 + 1) * bstep);
    }

    __syncthreads();  // A staged

    // ---- GEMM1 ----
#pragma unroll
    for (int kk = 0; kk < 8; ++kk) {
        bf16x8 bn[4];
        if (kk < 6) {
#pragma unroll
            for (int ct = 0; ct < 4; ++ct)
                bn[ct] = *(const bf16x8*)(w1b + ((size_t)ct * 8 + kk + 2) * bstep);
        }
        bf16x8 af[4];
#pragma unroll
        for (int rt = 0; rt < 4; ++rt) {
            int row = rt * 16 + l16;
            int c = kk * 4 + quad;
            int slot = (c & 24) | ((c & 7) ^ (row & 7));
            af[rt] = *(const bf16x8*)&tile[row * 256 + slot * 8];
        }
#pragma unroll
        for (int ct = 0; ct < 4; ++ct) {
#pragma unroll
            for (int rt = 0; rt < 4; ++rt)
                acc[rt][ct] = __builtin_amdgcn_mfma_f32_16x16x32_bf16(
                    af[rt], bp[kk & 1][ct], acc[rt][ct], 0, 0, 0);
        }
        if (kk < 6) {
#pragma unroll
            for (int ct = 0; ct < 4; ++ct) bp[kk & 1][ct] = bn[ct];
        }
    }
    __syncthreads();  // A reads done; reuse tile for h

    // prefetch GEMM2 B steps 0,1 (independent of LDS)
#pragma unroll
    for (int ct = 0; ct < 4; ++ct) {
        bp[0][ct] = *(const bf16x8*)(w2b + ((size_t)ct * 8 + 0) * bstep);
        bp[1][ct] = *(const bf16x8*)(w2b + ((size_t)ct * 8 + 1) * bstep);
    }

    // ---- h = relu(acc + b1) -> tile (swizzled bf16) ----
#pragma unroll
    for (int ct = 0; ct < 4; ++ct) {
        int colg = wave * 64 + ct * 16 + l16;
        float bv = b1[colg];
        int cc = colg >> 3;
        int off = colg & 7;
#pragma unroll
        for (int rt = 0; rt < 4; ++rt) {
#pragma unroll
            for (int reg = 0; reg < 4; ++reg) {
                int row = rt * 16 + quad * 4 + reg;
                int slot = (cc & 24) | ((cc & 7) ^ (row & 7));
                tile[row * 256 + slot * 8 + off] = f2b(fmaxf(acc[rt][ct][reg] + bv, 0.0f));
            }
        }
    }

#pragma unroll
    for (int rt = 0; rt < 4; ++rt)
#pragma unroll
        for (int ct = 0; ct < 4; ++ct) acc[rt][ct] = (f32x4){0.f, 0.f, 0.f, 0.f};

    __syncthreads();  // h visible

    // ---- GEMM2 ----
#pragma unroll
    for (int kk = 0; kk < 8; ++kk) {
        bf16x8 bn[4];
        if (kk < 6) {
#pragma unroll
            for (int ct = 0; ct < 4; ++ct)
                bn[ct] = *(const bf16x8*)(w2b + ((size_t)ct * 8 + kk + 2) * bstep);
        }
        bf16x8 af[4];
#pragma unroll
        for (int rt = 0; rt < 4; ++rt) {
            int row = rt * 16 + l16;
            int c = kk * 4 + quad;
            int slot = (c & 24) | ((c & 7) ^ (row & 7));
            af[rt] = *(const bf16x8*)&tile[row * 256 + slot * 8];
        }
#pragma unroll
        for (int ct = 0; ct < 4; ++ct) {
#pragma unroll
            for (int rt = 0; rt < 4; ++rt)
                acc[rt][ct] = __builtin_amdgcn_mfma_f32_16x16x32_bf16(
                    af[rt], bp[kk & 1][ct], acc[rt][ct], 0, 0, 0);
        }
        if (kk < 6) {
#pragma unroll
            for (int ct = 0; ct < 4; ++ct) bp[kk & 1][ct] = bn[ct];
        }
    }
    __syncthreads();  // h reads done; reuse tile for output

    // ---- out tile -> tile (swizzled), then coalesced dwordx4 store ----
#pragma unroll
    for (int ct = 0; ct < 4; ++ct) {
        int colg = wave * 64 + ct * 16 + l16;
        int cc = colg >> 3;
        int off = colg & 7;
#pragma unroll
        for (int rt = 0; rt < 4; ++rt) {
#pragma unroll
            for (int reg = 0; reg < 4; ++reg) {
                int row = rt * 16 + quad * 4 + reg;
                int slot = (cc & 24) | ((cc & 7) ^ (row & 7));
                tile[row * 256 + slot * 8 + off] = f2b(acc[rt][ct][reg]);
            }
        }
    }
    __syncthreads();
#pragma unroll
    for (int r = 0; r < 8; ++r) {
        int row = r * 8 + (tid >> 5);
        int c = tid & 31;
        int slot = (c & 24) | ((c & 7) ^ (row & 7));
        uint4 v = *(const uint4*)&tile[row * 256 + slot * 8];
        *(uint4*)(hw + (size_t)(bm + row) * 256 + c * 8) = v;
    }
}

// ================= host =================
extern "C" void kernel_launch(void* const* d_in, const int* in_sizes, int n_in,
                              void* d_out, int out_size, void* d_ws, size_t ws_size,
                              hipStream_t stream) {
    const float* x    = (const float*)d_in[0];
    const int*   ei   = (const int*)d_in[1];
    const float* w1_l = (const float*)d_in[2];
    const float* b1_l = (const float*)d_in[3];
    const float* w1_r = (const float*)d_in[4];
    const float* w2_l = (const float*)d_in[5];
    const float* b2_l = (const float*)d_in[6];
    const float* w2_r = (const float*)d_in[7];
    float* out = (float*)d_out;

    const int* src = ei;
    const int* dst = ei + N_EDGES;

    // ---- workspace ----
    int* cnt = (int*)d_ws;                                   // [N] (200000 B, 16-aligned)
    ushort* col = (ushort*)(cnt + N_NODES);                  // [N*CAP] ushort (6.4 MB)
    size_t ib = (size_t)N_NODES * 4 + (size_t)N_NODES * CAP * 2;
    size_t ofs = (ib + 15) & ~(size_t)15;
    ushort* xcat = (ushort*)((char*)d_ws + ofs);             // [M_PAD][256]: mean1|x
    ushort* hw   = xcat + (size_t)M_PAD * HID;               // [M_PAD][256]
    ushort* w1f  = hw + (size_t)M_PAD * HID;                 // [16][8][64][8]
    ushort* w2f  = w1f + HID * HID;                          // [16][8][64][8]

    hipMemsetAsync(cnt, 0, (size_t)N_NODES * sizeof(int), stream);

    // ---- bucket CSR + casts (one dispatch) ----
    prep<<<625 + 3637, 256, 0, stream>>>(src, dst, x, w1_l, w1_r, w2_l, w2_r,
                                         cnt, col, xcat, w1f, w2f);

    // ---- layer 1 gather, fused double-GEMM, layer 2 combine ----
    aggregate_mean1<<<N_NODES * 16 / 256, 256, 0, stream>>>(cnt, col, xcat);
    fused_gemm<<<M_PAD / 64, 256, 0, stream>>>(xcat, w1f, w2f, b1_l, hw);
    combine2<<<N_NODES * 16 / 256, 256, 0, stream>>>(hw, cnt, col, b2_l, out);
}